// Round 4
// baseline (174.480 us; speedup 1.0000x reference)
//
#include <hip/hip_runtime.h>

// DIAGNOSTIC ROUND: identical span kernel launched 3x (idempotent writes).
// Purpose: solve dur_us = overhead + N*K for K (kernel time), since the
// kernel's own rocprof row is hidden below the harness's 60-us poison fills.
// span(L,i)[b,d] = sum_{k=1..L} tensor[b, i+k, d] -> out[b, offL(L)+i, d]

__global__ __launch_bounds__(256) void span_sums_kernel(
    const float4* __restrict__ in,        // [B, S, D4]
    float4* __restrict__ out,             // [B, Ssum, D4]
    const int* __restrict__ maxspan_ptr)
{
    constexpr int B = 8, S = 512, D4 = 192;
    const int Lmax = *maxspan_ptr;

    const int tid = blockIdx.x * blockDim.x + threadIdx.x;
    const int total = B * (S - 1) * D4;     // 784,896 = 3066 * 256 exactly
    if (tid >= total) return;

    const int d4   = tid % D4;
    const int rest = tid / D4;
    const int i    = rest % (S - 1);        // span start = token 1+i
    const int b    = rest / (S - 1);

    const int Ssum = Lmax * S - (Lmax * (Lmax + 1)) / 2;   // 4060 for Lmax=8

    const float4* ip = in  + ((size_t)b * S    + (size_t)(i + 1)) * D4 + d4;
    float4*       op = out + ((size_t)b * Ssum + (size_t)i)       * D4 + d4;

    if (Lmax == 8 && i <= S - 1 - 8) {
        float4 v0 = ip[0 * D4];
        float4 v1 = ip[1 * D4];
        float4 v2 = ip[2 * D4];
        float4 v3 = ip[3 * D4];
        float4 v4 = ip[4 * D4];
        float4 v5 = ip[5 * D4];
        float4 v6 = ip[6 * D4];
        float4 v7 = ip[7 * D4];
        v1.x += v0.x; v1.y += v0.y; v1.z += v0.z; v1.w += v0.w;
        v2.x += v1.x; v2.y += v1.y; v2.z += v1.z; v2.w += v1.w;
        v3.x += v2.x; v3.y += v2.y; v3.z += v2.z; v3.w += v2.w;
        v4.x += v3.x; v4.y += v3.y; v4.z += v3.z; v4.w += v3.w;
        v5.x += v4.x; v5.y += v4.y; v5.z += v4.z; v5.w += v4.w;
        v6.x += v5.x; v6.y += v5.y; v6.z += v5.z; v6.w += v5.w;
        v7.x += v6.x; v7.y += v6.y; v7.z += v6.z; v7.w += v6.w;
        op[0    * D4] = v0;
        op[511  * D4] = v1;
        op[1021 * D4] = v2;
        op[1530 * D4] = v3;
        op[2038 * D4] = v4;
        op[2545 * D4] = v5;
        op[3051 * D4] = v6;
        op[3556 * D4] = v7;
    } else {
        int Lcap = S - 1 - i;
        if (Lcap > Lmax) Lcap = Lmax;
        float4 acc = make_float4(0.f, 0.f, 0.f, 0.f);
        size_t off = 0;
        for (int L = 1; L <= Lcap; ++L) {
            const float4 v = ip[(size_t)(L - 1) * D4];
            acc.x += v.x; acc.y += v.y; acc.z += v.z; acc.w += v.w;
            op[off] = acc;
            off += (size_t)(S - L) * D4;
        }
    }
}

extern "C" void kernel_launch(void* const* d_in, const int* in_sizes, int n_in,
                              void* d_out, int out_size, void* d_ws, size_t ws_size,
                              hipStream_t stream) {
    const float* tensor = (const float*)d_in[0];
    const int* maxspan = (const int*)d_in[1];
    float* out = (float*)d_out;

    constexpr int B = 8, S = 512, D4 = 192;
    const int total = B * (S - 1) * D4;            // 784,896
    const int block = 256;
    const int grid = (total + block - 1) / block;  // 3066

    // 3 identical idempotent launches: dur_us = overhead + 3*K.
    // Compare against R3's single-launch 121.3 us to solve for K.
    for (int rep = 0; rep < 3; ++rep) {
        span_sums_kernel<<<grid, block, 0, stream>>>(
            (const float4*)tensor, (float4*)out, maxspan);
    }
}

// Round 5
// 115.748 us; speedup vs baseline: 1.5074x; 1.5074x over previous
//
#include <hip/hip_runtime.h>

// span(L,i)[b,d] = sum_{k=1..L} tensor[b, i+k, d] -> out[b, offL(L)+i, d],
// offL(L) = (L-1)*S - (L-1)*L/2. B=8, S=512, D=768 (192 float4), Lmax=8.
// R5: pair two starts per thread. Thread (b,u,d4), u<252 -> i={2u, 2u+1}:
// 9 loads (rows i+1..i+9) -> prefix P1..P9 -> 16 stores
//   span(L, i)   = P_L
//   span(L, i+1) = P_{L+1} - P_1
// u in [252,259) -> single tail start i = 504+(u-252), generic loop.
// Measured R4: K ~= 26.6 us vs ~17 us traffic roofline; this halves load
// instructions + L2 read traffic and doubles per-thread work.

__device__ __forceinline__ float4 f4add(float4 a, float4 b) {
    return make_float4(a.x + b.x, a.y + b.y, a.z + b.z, a.w + b.w);
}
__device__ __forceinline__ float4 f4sub(float4 a, float4 b) {
    return make_float4(a.x - b.x, a.y - b.y, a.z - b.z, a.w - b.w);
}

__global__ __launch_bounds__(256) void span_pair_kernel(
    const float4* __restrict__ in,        // [B, S, D4]
    float4* __restrict__ out,             // [B, Ssum, D4]
    const int* __restrict__ maxspan_ptr)
{
    constexpr int S = 512, D4 = 192;
    constexpr int UPAIR = 252;            // u<252: pair (2u, 2u+1), i<=503 full-span
    constexpr int UTOT  = 259;            // 252 pairs + 7 tail singles (i=504..510)
    const int Lmax = *maxspan_ptr;        // wave-uniform

    const int tid = blockIdx.x * blockDim.x + threadIdx.x;
    const int total = 8 * UTOT * D4;      // 397,824 = 1554 * 256 exactly
    if (tid >= total) return;

    const int d4   = tid % D4;
    const int rest = tid / D4;
    const int u    = rest % UTOT;
    const int b    = rest / UTOT;

    const int Ssum = Lmax * S - (Lmax * (Lmax + 1)) / 2;   // 4060 for Lmax=8

    const float4* inb  = in  + (size_t)b * S    * D4 + d4;
    float4*       outb = out + (size_t)b * Ssum * D4 + d4;

    if (Lmax == 8 && u < UPAIR) {
        const int i = 2 * u;                          // 0..502
        const float4* ip = inb + (size_t)(i + 1) * D4;
        // 9 independent loads: rows i+1 .. i+9 (max row index 511 when i=502)
        float4 r0 = ip[0 * D4];
        float4 r1 = ip[1 * D4];
        float4 r2 = ip[2 * D4];
        float4 r3 = ip[3 * D4];
        float4 r4 = ip[4 * D4];
        float4 r5 = ip[5 * D4];
        float4 r6 = ip[6 * D4];
        float4 r7 = ip[7 * D4];
        float4 r8 = ip[8 * D4];
        // prefix sums P1..P9
        float4 p1 = r0;
        float4 p2 = f4add(p1, r1);
        float4 p3 = f4add(p2, r2);
        float4 p4 = f4add(p3, r3);
        float4 p5 = f4add(p4, r4);
        float4 p6 = f4add(p5, r5);
        float4 p7 = f4add(p6, r6);
        float4 p8 = f4add(p7, r7);
        float4 p9 = f4add(p8, r8);
        // row offsets offL(L) = {0,511,1021,1530,2038,2545,3051,3556}
        float4* o0 = outb + (size_t)i * D4;
        // span(L, i) = P_L
        o0[(0    + 0) * (size_t)D4] = p1;
        o0[(511  + 0) * (size_t)D4] = p2;
        o0[(1021 + 0) * (size_t)D4] = p3;
        o0[(1530 + 0) * (size_t)D4] = p4;
        o0[(2038 + 0) * (size_t)D4] = p5;
        o0[(2545 + 0) * (size_t)D4] = p6;
        o0[(3051 + 0) * (size_t)D4] = p7;
        o0[(3556 + 0) * (size_t)D4] = p8;
        // span(L, i+1) = P_{L+1} - P_1
        o0[(0    + 1) * (size_t)D4] = f4sub(p2, p1);
        o0[(511  + 1) * (size_t)D4] = f4sub(p3, p1);
        o0[(1021 + 1) * (size_t)D4] = f4sub(p4, p1);
        o0[(1530 + 1) * (size_t)D4] = f4sub(p5, p1);
        o0[(2038 + 1) * (size_t)D4] = f4sub(p6, p1);
        o0[(2545 + 1) * (size_t)D4] = f4sub(p7, p1);
        o0[(3051 + 1) * (size_t)D4] = f4sub(p8, p1);
        o0[(3556 + 1) * (size_t)D4] = f4sub(p9, p1);
    } else if (Lmax == 8) {
        // tail singles: i = 504..510, Lcap = 511-i in 1..7
        const int i = 504 + (u - UPAIR);
        const float4* ip = inb + (size_t)(i + 1) * D4;
        int Lcap = 511 - i;
        float4 acc = make_float4(0.f, 0.f, 0.f, 0.f);
        int offL = 0;
        for (int L = 1; L <= Lcap; ++L) {
            acc = f4add(acc, ip[(size_t)(L - 1) * D4]);
            outb[(size_t)(offL + i) * D4] = acc;
            offL += S - L;
        }
    } else {
        // fully generic (Lmax != 8): handle this u's 1-2 start indices
        const int i_first = (u < UPAIR) ? 2 * u : 504 + (u - UPAIR);
        const int n_i     = (u < UPAIR) ? 2 : 1;
        for (int k = 0; k < n_i; ++k) {
            const int i = i_first + k;
            if (i >= S - 1) break;
            const float4* ip = inb + (size_t)(i + 1) * D4;
            int Lcap = S - 1 - i;
            if (Lcap > Lmax) Lcap = Lmax;
            float4 acc = make_float4(0.f, 0.f, 0.f, 0.f);
            int offL = 0;
            for (int L = 1; L <= Lcap; ++L) {
                acc = f4add(acc, ip[(size_t)(L - 1) * D4]);
                outb[(size_t)(offL + i) * D4] = acc;
                offL += S - L;
            }
        }
    }
}

extern "C" void kernel_launch(void* const* d_in, const int* in_sizes, int n_in,
                              void* d_out, int out_size, void* d_ws, size_t ws_size,
                              hipStream_t stream) {
    const float* tensor = (const float*)d_in[0];
    const int* maxspan = (const int*)d_in[1];
    float* out = (float*)d_out;

    constexpr int D4 = 192, UTOT = 259;
    const int total = 8 * UTOT * D4;               // 397,824
    const int block = 256;
    const int grid = (total + block - 1) / block;  // 1554

    span_pair_kernel<<<grid, block, 0, stream>>>(
        (const float4*)tensor, (float4*)out, maxspan);
}